// Round 3
// baseline (184.967 us; speedup 1.0000x reference)
//
#include <hip/hip_runtime.h>

#define NN    4096
#define MAXD  32      // degree cap (WS k=4 max degree ~12)
#define WUNR  8       // fully-unrolled ELL width; rows with c>8 take tail loop
#define TB    4       // tokens per block (xs = [col][TB] transposed tile)
#define BLK   1024

// Phase 1: build padded ELL (column-major [j][o]) of W*M, deterministically.
// One wave per output row o; ballot + prefix popcount -> indices sorted
// ascending -> fixed fp32 summation order. float2 {idx bitcast, w}; padding {0,0}.
__global__ __launch_bounds__(64) void build_ell_kernel(
    const float* __restrict__ weight, const float* __restrict__ mask,
    float2* __restrict__ ell, int* __restrict__ cnt) {
  const int o = blockIdx.x;
  const int lane = threadIdx.x;
  if (lane < MAXD) {
    float2 z; z.x = __uint_as_float(0u); z.y = 0.0f;
    ell[(size_t)lane * NN + o] = z;
  }
  __syncthreads();
  const float* mrow = mask + (size_t)o * NN;
  const float* wrow = weight + (size_t)o * NN;
  int count = 0;
  for (int base = 0; base < NN; base += 64) {
    const float m = mrow[base + lane];
    const bool nz = (m != 0.0f);
    const unsigned long long bal = __ballot(nz);
    if (nz) {
      const int pos = count + __popcll(bal & ((1ull << lane) - 1ull));
      if (pos < MAXD) {
        float2 e;
        e.x = __uint_as_float((unsigned)(base + lane));
        e.y = wrow[base + lane] * m;   // m == 1.0 exactly
        ell[(size_t)pos * NN + o] = e;
      }
    }
    count += __popcll(bal);
  }
  if (lane == 0) cnt[o] = (count < MAXD) ? count : MAXD;
}

// Phase 2: SpMM, LDS tile transposed to [col][TB] so one ds_read_b128
// fetches all TB token values for an ELL index.
__global__ __launch_bounds__(BLK) void ws_spmm_kernel(
    const float* __restrict__ x, const float* __restrict__ bias,
    const float2* __restrict__ ell, const int* __restrict__ cnt,
    float* __restrict__ out) {
  __shared__ float4 xs[NN];                          // [col] -> {t0,t1,t2,t3}, 64 KiB
  const int tid = threadIdx.x;
  const size_t t0 = (size_t)blockIdx.x * TB;
  const float* __restrict__ xb = x + t0 * NN;

  // Stage transposed: lane <-> col; 4 coalesced dword loads + 1 b128 write per col.
#pragma unroll
  for (int i = 0; i < NN / BLK; ++i) {
    const int c = tid + i * BLK;
    float4 v;
    v.x = xb[0 * NN + c];
    v.y = xb[1 * NN + c];
    v.z = xb[2 * NN + c];
    v.w = xb[3 * NN + c];
    xs[c] = v;
  }
  __syncthreads();

#pragma unroll
  for (int ob = 0; ob < NN; ob += BLK) {
    const int o = ob + tid;
    const int c = cnt[o];

    float2 e[WUNR];
#pragma unroll
    for (int j = 0; j < WUNR; ++j)
      e[j] = ell[(size_t)j * NN + o];                // coalesced dwordx2, L2-hit

    float acc0 = 0.f, acc1 = 0.f, acc2 = 0.f, acc3 = 0.f;
#pragma unroll
    for (int j = 0; j < WUNR; ++j) {
      const unsigned ix = __float_as_uint(e[j].x);
      const float w = e[j].y;
      const float4 xv = xs[ix];                      // ds_read_b128: all 4 tokens
      acc0 = fmaf(xv.x, w, acc0);
      acc1 = fmaf(xv.y, w, acc1);
      acc2 = fmaf(xv.z, w, acc2);
      acc3 = fmaf(xv.w, w, acc3);
    }
    for (int j = WUNR; j < c; ++j) {                 // rare tail (degree > 8)
      const float2 et = ell[(size_t)j * NN + o];
      const unsigned ix = __float_as_uint(et.x);
      const float w = et.y;
      const float4 xv = xs[ix];
      acc0 = fmaf(xv.x, w, acc0);
      acc1 = fmaf(xv.y, w, acc1);
      acc2 = fmaf(xv.z, w, acc2);
      acc3 = fmaf(xv.w, w, acc3);
    }

    const float b = bias[o];
    float* op = out + t0 * NN + o;
    op[0]      = acc0 + b;
    op[NN]     = acc1 + b;
    op[2 * NN] = acc2 + b;
    op[3 * NN] = acc3 + b;
  }
}

extern "C" void kernel_launch(void* const* d_in, const int* in_sizes, int n_in,
                              void* d_out, int out_size, void* d_ws, size_t ws_size,
                              hipStream_t stream) {
  const float* x      = (const float*)d_in[0];
  const float* weight = (const float*)d_in[1];
  const float* bias   = (const float*)d_in[2];
  const float* mask   = (const float*)d_in[3];
  float* out = (float*)d_out;

  char* ws = (char*)d_ws;
  float2* ell = (float2*)ws;                                     // 1 MiB
  int*    cnt = (int*)(ws + (size_t)MAXD * NN * sizeof(float2)); // 16 KiB

  const int tokens = in_sizes[0] / NN;               // 16384

  build_ell_kernel<<<NN, 64, 0, stream>>>(weight, mask, ell, cnt);
  ws_spmm_kernel<<<tokens / TB, BLK, 0, stream>>>(x, bias, ell, cnt, out);
}